// Round 1
// baseline (745.164 us; speedup 1.0000x reference)
//
#include <hip/hip_runtime.h>
#include <hip/hip_fp16.h>

// GridSmoother: per-(batch,channel) CG solve of (I + graph-Laplacian) x = b
// on a 128x160 grid. One workgroup (512 threads = 8 waves) per system;
// 256 systems = 256 workgroups = 1 per CU. Entire CG state lives in
// registers; wave-edge column halos + reduction slots in LDS. Fixed 50
// iterations (kappa<=9 -> fp32 floor by ~40).
//
// Thread mapping: lane l holds rows 2l,2l+1 (wave spans all 128 rows);
// wave w holds columns [20w, 20w+20). Up/down neighbors: own register or
// __shfl +-1 lane. Left/right: own registers except wave edges (LDS halo).
// Weights packed fp16 (pairs per column) to fit the 256-VGPR budget.

#define GH 128
#define GW 160
#define NW 8
#define NCOL 20
#define NT 512
#define NITER 50

__device__ __forceinline__ float wave_sum(float v) {
  #pragma unroll
  for (int off = 32; off > 0; off >>= 1) v += __shfl_xor(v, off, 64);
  return v;
}

// Stencil: Ap = c + wxl*(c-left) + wxr*(c-right) + wyu*(c-up) + wyd*(c-down)
// Boundary terms vanish because the corresponding weight regs are zeroed.
// ACCUM may use c0,c1 (p values) and a0,a1 (Ap values).
#define STENCIL(ACCUM)                                                        \
  {                                                                           \
    const int wl_ = (wv + NW - 1) & (NW - 1);                                 \
    const int wr_ = (wv + 1) & (NW - 1);                                      \
    const float2 hl_ = *(const float2*)&haloR[wl_][i0];                       \
    const float2 hr_ = *(const float2*)&haloL[wr_][i0];                       \
    float lf0 = hl_.x, lf1 = hl_.y;                                           \
    float wxl0 = __low2float(wxlh), wxl1 = __high2float(wxlh);                \
    _Pragma("unroll")                                                         \
    for (int k = 0; k < NCOL; ++k) {                                          \
      const float c0 = p0[k], c1 = p1[k];                                     \
      const float rt0 = (k == NCOL - 1) ? hr_.x : p0[(k + 1) % NCOL];         \
      const float rt1 = (k == NCOL - 1) ? hr_.y : p1[(k + 1) % NCOL];         \
      const float up0 = __shfl_up(c1, 1, 64);   /* row i0-1 = lane-1's p1 */  \
      const float dn1 = __shfl_down(c0, 1, 64); /* row i1+1 = lane+1's p0 */  \
      const float wxr0 = __low2float(wxh[k]), wxr1 = __high2float(wxh[k]);    \
      const float wy0 = __low2float(wyh[k]), wy1 = __high2float(wyh[k]);      \
      const float wu0 = (k & 1) ? __high2float(wyu0h[k >> 1])                 \
                                : __low2float(wyu0h[k >> 1]);                 \
      const float a0 = c0 + wxl0 * (c0 - lf0) + wxr0 * (c0 - rt0) +           \
                       wu0 * (c0 - up0) + wy0 * (c0 - c1);                    \
      const float a1 = c1 + wxl1 * (c1 - lf1) + wxr1 * (c1 - rt1) +           \
                       wy0 * (c1 - c0) + wy1 * (c1 - dn1);                    \
      Ap0[k] = a0; Ap1[k] = a1;                                               \
      ACCUM;                                                                  \
      lf0 = c0; lf1 = c1; wxl0 = wxr0; wxl1 = wxr1;                           \
    }                                                                         \
  }

#define WRITE_HALO()                                                          \
  {                                                                           \
    *(float2*)&haloL[wv][i0] = make_float2(p0[0], p1[0]);                     \
    *(float2*)&haloR[wv][i0] = make_float2(p0[NCOL - 1], p1[NCOL - 1]);       \
  }

__global__ __launch_bounds__(NT) void GridSmoother_cg_kernel(
    const float* __restrict__ ae, const float* __restrict__ wxwy,
    float* __restrict__ out) {
  const int tid = threadIdx.x;
  const int wv = tid >> 6;
  const int lane = tid & 63;
  const int prob = blockIdx.x;  // b*16 + d
  const int bb = prob >> 4;

  const int i0 = lane << 1;
  const int i1 = i0 | 1;
  const int j0 = wv * NCOL;

  const float* __restrict__ bsrc = ae + (size_t)prob * (GH * GW);
  const float* __restrict__ wxp = wxwy + (size_t)(2 * bb) * (GH * GW);
  const float* __restrict__ wyp = wxp + (GH * GW);
  float* __restrict__ outp = out + (size_t)prob * (GH * GW);

  __shared__ float haloL[NW][GH];  // p at each wave's leftmost column
  __shared__ float haloR[NW][GH];  // p at each wave's rightmost column
  __shared__ float red[2][NW];     // cross-wave reduction slots

  float p0[NCOL], p1[NCOL], x0[NCOL], x1[NCOL], r0[NCOL], r1[NCOL];
  float Ap0[NCOL], Ap1[NCOL];
  __half2 wxh[NCOL];           // (wx[i0][j], wx[i1][j]) right weights
  __half2 wyh[NCOL];           // (wy[i0][j], wy[i1][j]) down weights
  __half2 wyu0h[NCOL / 2];     // up weight for row i0 (lane-1's wy[i1])
  __half2 wxlh;                // left-edge weight pair (col j0-1)

  // ---- load b;  x = p = b (jax cg uses x0 = b) ----
  {
    const float4* s0 = (const float4*)(bsrc + i0 * GW + j0);
    const float4* s1 = (const float4*)(bsrc + i1 * GW + j0);
    #pragma unroll
    for (int q = 0; q < NCOL / 4; ++q) {
      float4 v0 = s0[q], v1 = s1[q];
      p0[4 * q + 0] = v0.x; p0[4 * q + 1] = v0.y;
      p0[4 * q + 2] = v0.z; p0[4 * q + 3] = v0.w;
      p1[4 * q + 0] = v1.x; p1[4 * q + 1] = v1.y;
      p1[4 * q + 2] = v1.z; p1[4 * q + 3] = v1.w;
    }
  }
  #pragma unroll
  for (int k = 0; k < NCOL; ++k) { x0[k] = p0[k]; x1[k] = p1[k]; }

  // ---- load weights (zeroed at domain boundaries), pack to fp16 ----
  {
    float wy1t[NCOL];
    const float4* a0p = (const float4*)(wxp + i0 * GW + j0);
    const float4* a1p = (const float4*)(wxp + i1 * GW + j0);
    const float4* c0p = (const float4*)(wyp + i0 * GW + j0);
    const float4* c1p = (const float4*)(wyp + i1 * GW + j0);
    #pragma unroll
    for (int q = 0; q < NCOL / 4; ++q) {
      float4 a0 = a0p[q], a1 = a1p[q], c0 = c0p[q], c1 = c1p[q];
      const float e0[4] = {a0.x, a0.y, a0.z, a0.w};
      const float e1[4] = {a1.x, a1.y, a1.z, a1.w};
      const float f0[4] = {c0.x, c0.y, c0.z, c0.w};
      const float f1[4] = {c1.x, c1.y, c1.z, c1.w};
      #pragma unroll
      for (int e = 0; e < 4; ++e) {
        const int k = 4 * q + e;
        const bool lastcol = (j0 + k == GW - 1);  // wx_e excludes col W-1
        wxh[k] = __floats2half2_rn(lastcol ? 0.f : e0[e],
                                   lastcol ? 0.f : e1[e]);
        const float wyd0 = f0[e];                       // i0 <= 126 always
        const float wyd1 = (i1 == GH - 1) ? 0.f : f1[e]; // wy_e excludes row H-1
        wyh[k] = __floats2half2_rn(wyd0, wyd1);
        wy1t[k] = wyd1;
      }
    }
    #pragma unroll
    for (int q = 0; q < NCOL / 2; ++q) {
      float ua = __shfl_up(wy1t[2 * q + 0], 1, 64);
      float ub = __shfl_up(wy1t[2 * q + 1], 1, 64);
      if (lane == 0) { ua = 0.f; ub = 0.f; }  // row 0 has no up neighbor
      wyu0h[q] = __floats2half2_rn(ua, ub);
    }
    float wl0 = 0.f, wl1 = 0.f;
    if (wv > 0) {
      wl0 = wxp[i0 * GW + (j0 - 1)];
      wl1 = wxp[i1 * GW + (j0 - 1)];
    }
    wxlh = __floats2half2_rn(wl0, wl1);
  }

  // ---- r = b - A*b ; p = r ; rr_old = <r,r> ----
  WRITE_HALO();
  __syncthreads();
  STENCIL(;)
  float rr = 0.f;
  #pragma unroll
  for (int k = 0; k < NCOL; ++k) {
    r0[k] = x0[k] - Ap0[k];
    r1[k] = x1[k] - Ap1[k];
    rr += r0[k] * r0[k] + r1[k] * r1[k];
    p0[k] = r0[k]; p1[k] = r1[k];
  }
  rr = wave_sum(rr);
  if (lane == 0) red[1][wv] = rr;
  WRITE_HALO();  // halo of p = r
  __syncthreads();
  float rr_old = 0.f;
  #pragma unroll
  for (int q = 0; q < NW; ++q) rr_old += red[1][q];

  // ---- CG main loop: 3 barriers / iteration ----
  #pragma unroll 1
  for (int it = 0; it < NITER; ++it) {
    float pAp = 0.f;
    STENCIL(pAp += c0 * a0 + c1 * a1;)
    pAp = wave_sum(pAp);
    if (lane == 0) red[0][wv] = pAp;
    __syncthreads();
    float s = 0.f;
    #pragma unroll
    for (int q = 0; q < NW; ++q) s += red[0][q];
    const float alpha = rr_old / fmaxf(s, 1e-37f);

    float rrn_loc = 0.f;
    #pragma unroll
    for (int k = 0; k < NCOL; ++k) {
      x0[k] = fmaf(alpha, p0[k], x0[k]);
      x1[k] = fmaf(alpha, p1[k], x1[k]);
      r0[k] = fmaf(-alpha, Ap0[k], r0[k]);
      r1[k] = fmaf(-alpha, Ap1[k], r1[k]);
      rrn_loc += r0[k] * r0[k] + r1[k] * r1[k];
    }
    rrn_loc = wave_sum(rrn_loc);
    if (lane == 0) red[1][wv] = rrn_loc;
    __syncthreads();
    float rrn = 0.f;
    #pragma unroll
    for (int q = 0; q < NW; ++q) rrn += red[1][q];
    const float beta = rrn / fmaxf(rr_old, 1e-37f);
    rr_old = rrn;

    #pragma unroll
    for (int k = 0; k < NCOL; ++k) {
      p0[k] = fmaf(beta, p0[k], r0[k]);
      p1[k] = fmaf(beta, p1[k], r1[k]);
    }
    WRITE_HALO();
    __syncthreads();
  }

  // ---- store x ----
  {
    float4* o0 = (float4*)(outp + i0 * GW + j0);
    float4* o1 = (float4*)(outp + i1 * GW + j0);
    #pragma unroll
    for (int q = 0; q < NCOL / 4; ++q) {
      o0[q] = make_float4(x0[4 * q + 0], x0[4 * q + 1],
                          x0[4 * q + 2], x0[4 * q + 3]);
      o1[q] = make_float4(x1[4 * q + 0], x1[4 * q + 1],
                          x1[4 * q + 2], x1[4 * q + 3]);
    }
  }
}

extern "C" void kernel_launch(void* const* d_in, const int* in_sizes, int n_in,
                              void* d_out, int out_size, void* d_ws,
                              size_t ws_size, hipStream_t stream) {
  const float* ae = (const float*)d_in[0];      // (16,16,128,160) f32
  const float* wxwy = (const float*)d_in[1];    // (16,2,128,160) f32
  float* out = (float*)d_out;                   // (16,16,128,160) f32
  const int nprob = in_sizes[0] / (GH * GW);    // 256 systems
  GridSmoother_cg_kernel<<<dim3(nprob), dim3(NT), 0, stream>>>(ae, wxwy, out);
}

// Round 2
// 219.771 us; speedup vs baseline: 3.3906x; 3.3906x over previous
//
#include <hip/hip_runtime.h>
#include <hip/hip_fp16.h>

// GridSmoother: per-(batch,channel) CG solve of (I + graph-Laplacian) x = b
// on a 128x160 grid. One workgroup (512 threads = 8 waves) per system;
// 256 systems = 256 workgroups = 1 per CU. CG vectors p/r/Ap in registers,
// x in LDS (conflict-free [k][tid] layout); wave-edge column halos +
// reduction slots in LDS. Fixed 32 iterations (kappa<=9 -> 2*0.5^32 ~ 5e-10,
// far below the fp16-weight floor ~1.6e-2; threshold 7.8e-2).
//
// Thread mapping: lane l holds rows 2l,2l+1 (wave spans all 128 rows);
// wave w holds columns [20w, 20w+20). Up/down neighbors: own register or
// __shfl +-1 lane. Left/right: own registers except wave edges (LDS halo).
// Weights packed fp16 (pairs per column) to fit the 256-VGPR budget.
// __launch_bounds__(512, 2): 2 waves/EU -> 256-VGPR cap. Round-1 lesson:
// default launch_bounds capped at 128 VGPRs -> 1.4 GB/dispatch scratch spill.

#define GH 128
#define GW 160
#define NW 8
#define NCOL 20
#define NT 512
#define NITER 32

__device__ __forceinline__ float wave_sum(float v) {
  #pragma unroll
  for (int off = 32; off > 0; off >>= 1) v += __shfl_xor(v, off, 64);
  return v;
}

// Stencil: Ap = c + wxl*(c-left) + wxr*(c-right) + wyu*(c-up) + wyd*(c-down)
// Boundary terms vanish because the corresponding weight regs are zeroed.
// ACCUM may use c0,c1 (p values) and a0,a1 (Ap values).
#define STENCIL(ACCUM)                                                        \
  {                                                                           \
    const int wl_ = (wv + NW - 1) & (NW - 1);                                 \
    const int wr_ = (wv + 1) & (NW - 1);                                      \
    const float2 hl_ = *(const float2*)&haloR[wl_][i0];                       \
    const float2 hr_ = *(const float2*)&haloL[wr_][i0];                       \
    float lf0 = hl_.x, lf1 = hl_.y;                                           \
    float wxl0 = __low2float(wxlh), wxl1 = __high2float(wxlh);                \
    _Pragma("unroll")                                                         \
    for (int k = 0; k < NCOL; ++k) {                                          \
      const float c0 = p0[k], c1 = p1[k];                                     \
      const float rt0 = (k == NCOL - 1) ? hr_.x : p0[(k + 1) % NCOL];         \
      const float rt1 = (k == NCOL - 1) ? hr_.y : p1[(k + 1) % NCOL];         \
      const float up0 = __shfl_up(c1, 1, 64);   /* row i0-1 = lane-1's p1 */  \
      const float dn1 = __shfl_down(c0, 1, 64); /* row i1+1 = lane+1's p0 */  \
      const float wxr0 = __low2float(wxh[k]), wxr1 = __high2float(wxh[k]);    \
      const float wy0 = __low2float(wyh[k]), wy1 = __high2float(wyh[k]);      \
      const float wu0 = (k & 1) ? __high2float(wyu0h[k >> 1])                 \
                                : __low2float(wyu0h[k >> 1]);                 \
      const float a0 = c0 + wxl0 * (c0 - lf0) + wxr0 * (c0 - rt0) +           \
                       wu0 * (c0 - up0) + wy0 * (c0 - c1);                    \
      const float a1 = c1 + wxl1 * (c1 - lf1) + wxr1 * (c1 - rt1) +           \
                       wy0 * (c1 - c0) + wy1 * (c1 - dn1);                    \
      Ap0[k] = a0; Ap1[k] = a1;                                               \
      ACCUM;                                                                  \
      lf0 = c0; lf1 = c1; wxl0 = wxr0; wxl1 = wxr1;                           \
    }                                                                         \
  }

#define WRITE_HALO()                                                          \
  {                                                                           \
    *(float2*)&haloL[wv][i0] = make_float2(p0[0], p1[0]);                     \
    *(float2*)&haloR[wv][i0] = make_float2(p0[NCOL - 1], p1[NCOL - 1]);       \
  }

__global__ __launch_bounds__(NT, 2) void GridSmoother_cg_kernel(
    const float* __restrict__ ae, const float* __restrict__ wxwy,
    float* __restrict__ out) {
  const int tid = threadIdx.x;
  const int wv = tid >> 6;
  const int lane = tid & 63;
  const int prob = blockIdx.x;  // b*16 + d
  const int bb = prob >> 4;

  const int i0 = lane << 1;
  const int i1 = i0 | 1;
  const int j0 = wv * NCOL;

  const float* __restrict__ bsrc = ae + (size_t)prob * (GH * GW);
  const float* __restrict__ wxp = wxwy + (size_t)(2 * bb) * (GH * GW);
  const float* __restrict__ wyp = wxp + (GH * GW);
  float* __restrict__ outp = out + (size_t)prob * (GH * GW);

  __shared__ float haloL[NW][GH];  // p at each wave's leftmost column
  __shared__ float haloR[NW][GH];  // p at each wave's rightmost column
  __shared__ float red[2][NW];     // cross-wave reduction slots
  __shared__ float xs0[NCOL][NT];  // x for row i0, [k][tid]: conflict-free
  __shared__ float xs1[NCOL][NT];  // x for row i1

  float p0[NCOL], p1[NCOL], r0[NCOL], r1[NCOL];
  float Ap0[NCOL], Ap1[NCOL];
  __half2 wxh[NCOL];           // (wx[i0][j], wx[i1][j]) right weights
  __half2 wyh[NCOL];           // (wy[i0][j], wy[i1][j]) down weights
  __half2 wyu0h[NCOL / 2];     // up weight for row i0 (lane-1's wy[i1])
  __half2 wxlh;                // left-edge weight pair (col j0-1)

  // ---- load b;  x = p = b (jax cg uses x0 = b) ----
  {
    const float4* s0 = (const float4*)(bsrc + i0 * GW + j0);
    const float4* s1 = (const float4*)(bsrc + i1 * GW + j0);
    #pragma unroll
    for (int q = 0; q < NCOL / 4; ++q) {
      float4 v0 = s0[q], v1 = s1[q];
      p0[4 * q + 0] = v0.x; p0[4 * q + 1] = v0.y;
      p0[4 * q + 2] = v0.z; p0[4 * q + 3] = v0.w;
      p1[4 * q + 0] = v1.x; p1[4 * q + 1] = v1.y;
      p1[4 * q + 2] = v1.z; p1[4 * q + 3] = v1.w;
    }
  }
  #pragma unroll
  for (int k = 0; k < NCOL; ++k) { xs0[k][tid] = p0[k]; xs1[k][tid] = p1[k]; }

  // ---- load weights (zeroed at domain boundaries), pack to fp16 ----
  {
    float wy1t[NCOL];
    const float4* a0p = (const float4*)(wxp + i0 * GW + j0);
    const float4* a1p = (const float4*)(wxp + i1 * GW + j0);
    const float4* c0p = (const float4*)(wyp + i0 * GW + j0);
    const float4* c1p = (const float4*)(wyp + i1 * GW + j0);
    #pragma unroll
    for (int q = 0; q < NCOL / 4; ++q) {
      float4 a0 = a0p[q], a1 = a1p[q], c0 = c0p[q], c1 = c1p[q];
      const float e0[4] = {a0.x, a0.y, a0.z, a0.w};
      const float e1[4] = {a1.x, a1.y, a1.z, a1.w};
      const float f0[4] = {c0.x, c0.y, c0.z, c0.w};
      const float f1[4] = {c1.x, c1.y, c1.z, c1.w};
      #pragma unroll
      for (int e = 0; e < 4; ++e) {
        const int k = 4 * q + e;
        const bool lastcol = (j0 + k == GW - 1);  // wx_e excludes col W-1
        wxh[k] = __floats2half2_rn(lastcol ? 0.f : e0[e],
                                   lastcol ? 0.f : e1[e]);
        const float wyd0 = f0[e];                       // i0 <= 126 always
        const float wyd1 = (i1 == GH - 1) ? 0.f : f1[e]; // wy_e excludes row H-1
        wyh[k] = __floats2half2_rn(wyd0, wyd1);
        wy1t[k] = wyd1;
      }
    }
    #pragma unroll
    for (int q = 0; q < NCOL / 2; ++q) {
      float ua = __shfl_up(wy1t[2 * q + 0], 1, 64);
      float ub = __shfl_up(wy1t[2 * q + 1], 1, 64);
      if (lane == 0) { ua = 0.f; ub = 0.f; }  // row 0 has no up neighbor
      wyu0h[q] = __floats2half2_rn(ua, ub);
    }
    float wl0 = 0.f, wl1 = 0.f;
    if (wv > 0) {
      wl0 = wxp[i0 * GW + (j0 - 1)];
      wl1 = wxp[i1 * GW + (j0 - 1)];
    }
    wxlh = __floats2half2_rn(wl0, wl1);
  }

  // ---- r = b - A*b ; p = r ; rr_old = <r,r> ----
  WRITE_HALO();
  __syncthreads();
  STENCIL(;)
  float rr = 0.f;
  #pragma unroll
  for (int k = 0; k < NCOL; ++k) {
    r0[k] = p0[k] - Ap0[k];   // x == p == b here
    r1[k] = p1[k] - Ap1[k];
    rr += r0[k] * r0[k] + r1[k] * r1[k];
    p0[k] = r0[k]; p1[k] = r1[k];
  }
  rr = wave_sum(rr);
  if (lane == 0) red[1][wv] = rr;
  WRITE_HALO();  // halo of p = r
  __syncthreads();
  float rr_old = 0.f;
  #pragma unroll
  for (int q = 0; q < NW; ++q) rr_old += red[1][q];

  // ---- CG main loop: 3 barriers / iteration ----
  #pragma unroll 1
  for (int it = 0; it < NITER; ++it) {
    float pAp = 0.f;
    STENCIL(pAp += c0 * a0 + c1 * a1;)
    pAp = wave_sum(pAp);
    if (lane == 0) red[0][wv] = pAp;
    __syncthreads();
    float s = 0.f;
    #pragma unroll
    for (int q = 0; q < NW; ++q) s += red[0][q];
    const float alpha = rr_old / fmaxf(s, 1e-37f);

    float rrn_loc = 0.f;
    #pragma unroll
    for (int k = 0; k < NCOL; ++k) {
      xs0[k][tid] = fmaf(alpha, p0[k], xs0[k][tid]);
      xs1[k][tid] = fmaf(alpha, p1[k], xs1[k][tid]);
      r0[k] = fmaf(-alpha, Ap0[k], r0[k]);
      r1[k] = fmaf(-alpha, Ap1[k], r1[k]);
      rrn_loc += r0[k] * r0[k] + r1[k] * r1[k];
    }
    rrn_loc = wave_sum(rrn_loc);
    if (lane == 0) red[1][wv] = rrn_loc;
    __syncthreads();
    float rrn = 0.f;
    #pragma unroll
    for (int q = 0; q < NW; ++q) rrn += red[1][q];
    const float beta = rrn / fmaxf(rr_old, 1e-37f);
    rr_old = rrn;

    #pragma unroll
    for (int k = 0; k < NCOL; ++k) {
      p0[k] = fmaf(beta, p0[k], r0[k]);
      p1[k] = fmaf(beta, p1[k], r1[k]);
    }
    WRITE_HALO();
    __syncthreads();
  }

  // ---- store x (each thread reads only its own LDS slots) ----
  {
    float4* o0 = (float4*)(outp + i0 * GW + j0);
    float4* o1 = (float4*)(outp + i1 * GW + j0);
    #pragma unroll
    for (int q = 0; q < NCOL / 4; ++q) {
      o0[q] = make_float4(xs0[4 * q + 0][tid], xs0[4 * q + 1][tid],
                          xs0[4 * q + 2][tid], xs0[4 * q + 3][tid]);
      o1[q] = make_float4(xs1[4 * q + 0][tid], xs1[4 * q + 1][tid],
                          xs1[4 * q + 2][tid], xs1[4 * q + 3][tid]);
    }
  }
}

extern "C" void kernel_launch(void* const* d_in, const int* in_sizes, int n_in,
                              void* d_out, int out_size, void* d_ws,
                              size_t ws_size, hipStream_t stream) {
  const float* ae = (const float*)d_in[0];      // (16,16,128,160) f32
  const float* wxwy = (const float*)d_in[1];    // (16,2,128,160) f32
  float* out = (float*)d_out;                   // (16,16,128,160) f32
  const int nprob = in_sizes[0] / (GH * GW);    // 256 systems
  GridSmoother_cg_kernel<<<dim3(nprob), dim3(NT), 0, stream>>>(ae, wxwy, out);
}